// Round 6
// baseline (293.070 us; speedup 1.0000x reference)
//
#include <hip/hip_runtime.h>
#include <hip/hip_bf16.h>
#include <math.h>

// ---------------------------------------------------------------------------
// GAT 2-layer forward, MI355X.
// R5->R6: layer-1 aggregation moved to x-space. GAT L1 is linear in h:
//   sum(alpha*h1[s]) = (sum(alpha*x[s])) @ W1   (per head)
// so agg1 gathers 256B x-rows instead of 512B h1-rows (halves its gather
// bytes — R5 showed agg byte-bound at ~5.1 TB/s logical). el1/er1 computed
// pre-GEMM via folded Q[k][h] = W1_h @ a1[h], fused into the x->bf16 convert
// pass (xprep). New per-head MFMA GEMM (A1_h @ W1_h + b1, relu) -> h1rb.
// Layer 2 unchanged (gather h2 256B rows is already minimal there).
//   CSR: hist -> scan(a,b,c+end) -> scatter
//   wprep: W1th[4][64][128], Q[128][8], W2t[128][256]  (bf16/f32)
//   xprep: x->xb bf16 + el1/er1 = x . Q
//   agg1x(xb) -> A1[N][4][128] bf16 ; gemm1h -> h1rb ; gemm2 -> h2b
//   dots_h1(h2b) -> el2,er2 ; agg2(h2b) -> out f32
// ---------------------------------------------------------------------------

#define NEG_SLOPE 0.2f

typedef short short8 __attribute__((ext_vector_type(8)));
typedef float float4v __attribute__((ext_vector_type(4)));

static __device__ __forceinline__ float lrelu(float v) {
    return v > 0.f ? v : NEG_SLOPE * v;
}

static __device__ __forceinline__ unsigned short f2bf(float f) {
    unsigned int u = __float_as_uint(f);
    u = (u + 0x7fffu + ((u >> 16) & 1u)) >> 16;
    return (unsigned short)u;
}
static __device__ __forceinline__ float bf2f(unsigned int lo16) {
    return __uint_as_float(lo16 << 16);
}

// ---------------------------- CSR build ------------------------------------

__global__ void hist_kernel(const int* __restrict__ dst, int* __restrict__ cnt, int E) {
    int e = blockIdx.x * blockDim.x + threadIdx.x;
    if (e < E) atomicAdd(&cnt[dst[e]], 1);
}

__global__ void scan_a_kernel(const int* __restrict__ cnt, int* __restrict__ bsum, int N) {
    __shared__ int sdata[256];
    int t = threadIdx.x;
    int i = blockIdx.x * 256 + t;
    sdata[t] = (i < N) ? cnt[i] : 0;
    __syncthreads();
    for (int off = 128; off > 0; off >>= 1) {
        if (t < off) sdata[t] += sdata[t + off];
        __syncthreads();
    }
    if (t == 0) bsum[blockIdx.x] = sdata[0];
}

__global__ void scan_b_kernel(const int* __restrict__ bsum, int* __restrict__ boff, int nch) {
    __shared__ int s[256];
    int t = threadIdx.x;
    int v = (t < nch) ? bsum[t] : 0;
    s[t] = v;
    __syncthreads();
    for (int off = 1; off < 256; off <<= 1) {
        int add = (t >= off) ? s[t - off] : 0;
        __syncthreads();
        s[t] += add;
        __syncthreads();
    }
    boff[t] = s[t] - v;  // exclusive
}

__global__ void scan_c_kernel(const int* __restrict__ cnt, const int* __restrict__ boff,
                              int* __restrict__ row_start, int N, int E) {
    __shared__ int s[256];
    int t = threadIdx.x;
    int i = blockIdx.x * 256 + t;
    int v = (i < N) ? cnt[i] : 0;
    s[t] = v;
    __syncthreads();
    for (int off = 1; off < 256; off <<= 1) {
        int add = (t >= off) ? s[t - off] : 0;
        __syncthreads();
        s[t] += add;
        __syncthreads();
    }
    if (i < N) row_start[i] = s[t] - v + boff[blockIdx.x];
    if (i == N - 1) row_start[N] = E;
}

__global__ void scatter_kernel(const int* __restrict__ src, const int* __restrict__ dst,
                               const int* __restrict__ row_start, int* __restrict__ fill,
                               int* __restrict__ srcs, int E) {
    int e = blockIdx.x * blockDim.x + threadIdx.x;
    if (e < E) {
        int d = dst[e];
        int pos = row_start[d] + atomicAdd(&fill[d], 1);
        srcs[pos] = src[e];
    }
}

// ---------------------------- weight prep ----------------------------------
// W1 [128][256] f32 -> W1th [4][64][128] bf16 (per-head transposed)
// Q [128][8] f32: Q[k][h]   = sum_d W1[k][h*64+d]*al1[h][d]
//                 Q[k][4+h] = sum_d W1[k][h*64+d]*ar1[h][d]
// W2 [256][128] f32 -> W2t [128][256] bf16

__global__ void wprep_kernel(const float* __restrict__ W1, const float* __restrict__ al1,
                             const float* __restrict__ ar1, const float* __restrict__ W2,
                             unsigned short* __restrict__ W1th, float* __restrict__ Q,
                             unsigned short* __restrict__ W2t) {
    int idx = blockIdx.x * 256 + threadIdx.x;
    if (idx < 32768) {                       // W1th
        int h = idx >> 13;                   // /8192
        int r = idx & 8191;
        int d = r >> 7, k = r & 127;
        W1th[idx] = f2bf(W1[k * 256 + h * 64 + d]);
    } else if (idx < 32768 + 1024) {         // Q
        int j = idx - 32768;
        int k = j >> 3, c = j & 7;
        int h = c & 3;
        const float* av = (c < 4) ? al1 : ar1;
        const float* wrow = W1 + k * 256 + h * 64;
        float s = 0.f;
        #pragma unroll 8
        for (int d = 0; d < 64; ++d) s += wrow[d] * av[h * 64 + d];
        Q[k * 8 + c] = s;
    } else if (idx < 32768 + 1024 + 32768) { // W2t
        int j = idx - 33792;
        int m = j >> 8, k = j & 255;
        W2t[(size_t)m * 256 + k] = f2bf(W2[(size_t)k * 128 + m]);
    }
}

// ---------------------------- xprep: cvt + L1 dots -------------------------
// wave per node (grid-stride). lane covers k=2*lane, 2*lane+1.

__global__ __launch_bounds__(256) void xprep_kernel(const float* __restrict__ x,
                             const float* __restrict__ Q, unsigned short* __restrict__ xb,
                             float* __restrict__ el, float* __restrict__ er, int N) {
    const int lane = threadIdx.x & 63;
    const int gw = (blockIdx.x * 256 + threadIdx.x) >> 6;
    const int nw = gridDim.x * 4;
    const float4* Q4 = (const float4*)Q;
    const float4 qla = Q4[4 * lane + 0];   // ql[h], k=2*lane
    const float4 qra = Q4[4 * lane + 1];   // qr[h], k=2*lane
    const float4 qlb = Q4[4 * lane + 2];   // ql[h], k=2*lane+1
    const float4 qrb = Q4[4 * lane + 3];   // qr[h], k=2*lane+1

    for (int n = gw; n < N; n += nw) {
        float2 xv = *(const float2*)(x + (size_t)n * 128 + lane * 2);
        unsigned int pk = (unsigned int)f2bf(xv.x) | ((unsigned int)f2bf(xv.y) << 16);
        *(unsigned int*)(xb + (size_t)n * 128 + lane * 2) = pk;
        float l0 = xv.x * qla.x + xv.y * qlb.x;
        float l1 = xv.x * qla.y + xv.y * qlb.y;
        float l2 = xv.x * qla.z + xv.y * qlb.z;
        float l3 = xv.x * qla.w + xv.y * qlb.w;
        float r0 = xv.x * qra.x + xv.y * qrb.x;
        float r1 = xv.x * qra.y + xv.y * qrb.y;
        float r2 = xv.x * qra.z + xv.y * qrb.z;
        float r3 = xv.x * qra.w + xv.y * qrb.w;
        #pragma unroll
        for (int mask = 1; mask < 64; mask <<= 1) {
            l0 += __shfl_xor(l0, mask); l1 += __shfl_xor(l1, mask);
            l2 += __shfl_xor(l2, mask); l3 += __shfl_xor(l3, mask);
            r0 += __shfl_xor(r0, mask); r1 += __shfl_xor(r1, mask);
            r2 += __shfl_xor(r2, mask); r3 += __shfl_xor(r3, mask);
        }
        if (lane == 0) {
            *(float4*)(el + (size_t)n * 4) = make_float4(l0, l1, l2, l3);
            *(float4*)(er + (size_t)n * 4) = make_float4(r0, r1, r2, r3);
        }
    }
}

// ---------------------------- agg1 in x-space ------------------------------
// One wave per dst node. Gathers 256B xb rows; 4 per-head f32 accumulators.
// Output A1[n][h][128] bf16 (normalized weighted x-sum; bias/relu in gemm1h).

__global__ __launch_bounds__(256) void agg1x_kernel(const unsigned short* __restrict__ xb,
                            const float* __restrict__ el, const float* __restrict__ er,
                            const int* __restrict__ srcs, const int* __restrict__ row_start,
                            unsigned short* __restrict__ A1, int N) {
    int wave = (blockIdx.x * blockDim.x + threadIdx.x) >> 6;
    int lane = threadIdx.x & 63;
    if (wave >= N) return;
    const int n = wave;
    const int rs = row_start[n];
    const int re = row_start[n + 1];
    const int deg = re - rs;

    float acc[8];  // [h][2]
    #pragma unroll
    for (int j = 0; j < 8; ++j) acc[j] = 0.f;

    if (deg > 0) {
        const int cnt0 = deg < 64 ? deg : 64;
        const float4 ern = *(const float4*)(er + (size_t)n * 4);
        int sv = 0;
        float e0 = -INFINITY, e1 = -INFINITY, e2 = -INFINITY, e3 = -INFINITY;
        if (lane < cnt0) {
            sv = srcs[rs + lane];
            float4 ev = *(const float4*)(el + (size_t)sv * 4);
            e0 = lrelu(ev.x + ern.x);
            e1 = lrelu(ev.y + ern.y);
            e2 = lrelu(ev.z + ern.z);
            e3 = lrelu(ev.w + ern.w);
        }
        float m0 = e0, m1 = e1, m2 = e2, m3 = e3;
        for (int base = rs + 64; base < re; base += 64) {  // rare
            int idx = base + lane;
            if (idx < re) {
                int s = srcs[idx];
                float4 ev = *(const float4*)(el + (size_t)s * 4);
                m0 = fmaxf(m0, lrelu(ev.x + ern.x));
                m1 = fmaxf(m1, lrelu(ev.y + ern.y));
                m2 = fmaxf(m2, lrelu(ev.z + ern.z));
                m3 = fmaxf(m3, lrelu(ev.w + ern.w));
            }
        }
        #pragma unroll
        for (int mask = 1; mask < 64; mask <<= 1) {
            m0 = fmaxf(m0, __shfl_xor(m0, mask));
            m1 = fmaxf(m1, __shfl_xor(m1, mask));
            m2 = fmaxf(m2, __shfl_xor(m2, mask));
            m3 = fmaxf(m3, __shfl_xor(m3, mask));
        }
        float a0 = __expf(e0 - m0), a1 = __expf(e1 - m1);
        float a2 = __expf(e2 - m2), a3 = __expf(e3 - m3);
        float d0 = a0, d1 = a1, d2 = a2, d3 = a3;
        #pragma unroll
        for (int mask = 1; mask < 64; mask <<= 1) {
            d0 += __shfl_xor(d0, mask);
            d1 += __shfl_xor(d1, mask);
            d2 += __shfl_xor(d2, mask);
            d3 += __shfl_xor(d3, mask);
        }
        // fallback: deg > 64 (essentially never; Poisson(16))
        for (int idx = rs + 64; idx < re; ++idx) {
            int s = srcs[idx];
            float4 ev = *(const float4*)(el + (size_t)s * 4);
            float a0_ = __expf(lrelu(ev.x + ern.x) - m0);
            float a1_ = __expf(lrelu(ev.y + ern.y) - m1);
            float a2_ = __expf(lrelu(ev.z + ern.z) - m2);
            float a3_ = __expf(lrelu(ev.w + ern.w) - m3);
            d0 += a0_; d1 += a1_; d2 += a2_; d3 += a3_;
            unsigned int v = *(const unsigned int*)(xb + (size_t)s * 128 + lane * 2);
            float x0 = bf2f(v & 0xffffu), x1 = bf2f(v >> 16);
            acc[0] += a0_ * x0; acc[1] += a0_ * x1;
            acc[2] += a1_ * x0; acc[3] += a1_ * x1;
            acc[4] += a2_ * x0; acc[5] += a2_ * x1;
            acc[6] += a3_ * x0; acc[7] += a3_ * x1;
        }
        // pass 2: register-staged edges, x4 unrolled 256B gathers
        int i = 0;
        for (; i + 4 <= cnt0; i += 4) {
            int s0 = __shfl(sv, i), s1 = __shfl(sv, i + 1);
            int s2 = __shfl(sv, i + 2), s3 = __shfl(sv, i + 3);
            float w00 = __shfl(a0, i), w01 = __shfl(a1, i), w02 = __shfl(a2, i), w03 = __shfl(a3, i);
            float w10 = __shfl(a0, i + 1), w11 = __shfl(a1, i + 1), w12 = __shfl(a2, i + 1), w13 = __shfl(a3, i + 1);
            float w20 = __shfl(a0, i + 2), w21 = __shfl(a1, i + 2), w22 = __shfl(a2, i + 2), w23 = __shfl(a3, i + 2);
            float w30 = __shfl(a0, i + 3), w31 = __shfl(a1, i + 3), w32 = __shfl(a2, i + 3), w33 = __shfl(a3, i + 3);
            unsigned int v0 = *(const unsigned int*)(xb + (size_t)s0 * 128 + lane * 2);
            unsigned int v1 = *(const unsigned int*)(xb + (size_t)s1 * 128 + lane * 2);
            unsigned int v2 = *(const unsigned int*)(xb + (size_t)s2 * 128 + lane * 2);
            unsigned int v3 = *(const unsigned int*)(xb + (size_t)s3 * 128 + lane * 2);
            float x00 = bf2f(v0 & 0xffffu), x01 = bf2f(v0 >> 16);
            float x10 = bf2f(v1 & 0xffffu), x11 = bf2f(v1 >> 16);
            float x20 = bf2f(v2 & 0xffffu), x21 = bf2f(v2 >> 16);
            float x30 = bf2f(v3 & 0xffffu), x31 = bf2f(v3 >> 16);
            acc[0] += w00 * x00 + w10 * x10 + w20 * x20 + w30 * x30;
            acc[1] += w00 * x01 + w10 * x11 + w20 * x21 + w30 * x31;
            acc[2] += w01 * x00 + w11 * x10 + w21 * x20 + w31 * x30;
            acc[3] += w01 * x01 + w11 * x11 + w21 * x21 + w31 * x31;
            acc[4] += w02 * x00 + w12 * x10 + w22 * x20 + w32 * x30;
            acc[5] += w02 * x01 + w12 * x11 + w22 * x21 + w32 * x31;
            acc[6] += w03 * x00 + w13 * x10 + w23 * x20 + w33 * x30;
            acc[7] += w03 * x01 + w13 * x11 + w23 * x21 + w33 * x31;
        }
        for (; i < cnt0; ++i) {
            int s0 = __shfl(sv, i);
            float w0 = __shfl(a0, i), w1 = __shfl(a1, i), w2 = __shfl(a2, i), w3 = __shfl(a3, i);
            unsigned int v = *(const unsigned int*)(xb + (size_t)s0 * 128 + lane * 2);
            float x0 = bf2f(v & 0xffffu), x1 = bf2f(v >> 16);
            acc[0] += w0 * x0; acc[1] += w0 * x1;
            acc[2] += w1 * x0; acc[3] += w1 * x1;
            acc[4] += w2 * x0; acc[5] += w2 * x1;
            acc[6] += w3 * x0; acc[7] += w3 * x1;
        }
        float i0 = 1.f / d0, i1 = 1.f / d1, i2 = 1.f / d2, i3 = 1.f / d3;
        acc[0] *= i0; acc[1] *= i0;
        acc[2] *= i1; acc[3] *= i1;
        acc[4] *= i2; acc[5] *= i2;
        acc[6] *= i3; acc[7] *= i3;
    }
    #pragma unroll
    for (int h = 0; h < 4; ++h) {
        unsigned int pk = (unsigned int)f2bf(acc[h * 2]) |
                          ((unsigned int)f2bf(acc[h * 2 + 1]) << 16);
        *(unsigned int*)(A1 + (size_t)n * 512 + h * 128 + lane * 2) = pk;
    }
}

// ---------------------------- per-head GEMM1 (bf16 MFMA) -------------------
// h1rb[n][h*64+c] = relu( A1[n][h] @ W1th[h]^T [c] + b1[h*64+c] )
// Block: 64 rows x 64 cols of one head. grid (nrowb, 1, 4).

__global__ __launch_bounds__(256) void gemm1h_kernel(
        const unsigned short* __restrict__ A1,    // [N][4][128] bf16
        const unsigned short* __restrict__ W1th,  // [4][64][128] bf16
        const float* __restrict__ b1,             // [256] f32
        unsigned short* __restrict__ h1rb,        // [N][256] bf16
        int N) {
    constexpr int KP = 136;
    __shared__ unsigned short As[64 * KP];
    __shared__ unsigned short Bs[64 * KP];
    const int tid = threadIdx.x;
    const int wid = tid >> 6;
    const int lane = tid & 63;
    const int r0 = blockIdx.x * 64;
    const int h = blockIdx.z;

    for (int ch = tid; ch < 64 * 16; ch += 256) {
        int row = ch >> 4, kc = ch & 15;
        int gr = r0 + row;
        short8 v = {};
        if (gr < N) v = *(const short8*)(A1 + (size_t)gr * 512 + h * 128 + kc * 8);
        *(short8*)(As + row * KP + kc * 8) = v;
    }
    for (int ch = tid; ch < 64 * 16; ch += 256) {
        int row = ch >> 4, kc = ch & 15;
        *(short8*)(Bs + row * KP + kc * 8) =
            *(const short8*)(W1th + (size_t)h * 8192 + row * 128 + kc * 8);
    }
    __syncthreads();

    float4v acc[4];
    #pragma unroll
    for (int fr = 0; fr < 4; ++fr) acc[fr] = (float4v){0.f, 0.f, 0.f, 0.f};

    const int lr = lane & 15;
    const int lk = (lane >> 4) * 8;
    const int cw = wid * 16;

    #pragma unroll
    for (int ks = 0; ks < 128; ks += 32) {
        short8 bfr = *(const short8*)(Bs + (cw + lr) * KP + ks + lk);
        #pragma unroll
        for (int fr = 0; fr < 4; ++fr) {
            short8 af = *(const short8*)(As + (fr * 16 + lr) * KP + ks + lk);
            acc[fr] = __builtin_amdgcn_mfma_f32_16x16x32_bf16(af, bfr, acc[fr], 0, 0, 0);
        }
    }

    const int col = h * 64 + cw + lr;
    const float bias = b1[col];
    const int rbase = r0 + (lane >> 4) * 4;
    #pragma unroll
    for (int fr = 0; fr < 4; ++fr) {
        #pragma unroll
        for (int j = 0; j < 4; ++j) {
            int row = rbase + fr * 16 + j;
            if (row < N)
                h1rb[(size_t)row * 256 + col] = f2bf(fmaxf(acc[fr][j] + bias, 0.f));
        }
    }
}

// ---------------------------- GEMM2 (bf16 MFMA) ----------------------------

template <int K, int MSLICE>
__global__ __launch_bounds__(256) void mfma_gemm_kernel(
        const unsigned short* __restrict__ A,   // [N][K] bf16
        const unsigned short* __restrict__ Bt,  // [Mtot][K] bf16
        unsigned short* __restrict__ C,         // [N][Mtot] bf16
        int N, int Mtot) {
    constexpr int KP = K + 8;
    constexpr int CF = MSLICE / 64;
    constexpr int KC = K / 8;
    __shared__ unsigned short As[64 * KP];
    __shared__ unsigned short Bs[MSLICE * KP];
    const int tid = threadIdx.x;
    const int wid = tid >> 6;
    const int lane = tid & 63;
    const int r0 = blockIdx.x * 64;
    const int c0 = blockIdx.y * MSLICE;

    for (int ch = tid; ch < 64 * KC; ch += 256) {
        int row = ch / KC, kc = ch - row * KC;
        int gr = r0 + row;
        short8 v = {};
        if (gr < N) v = *(const short8*)(A + (size_t)gr * K + kc * 8);
        *(short8*)(As + row * KP + kc * 8) = v;
    }
    for (int ch = tid; ch < MSLICE * KC; ch += 256) {
        int row = ch / KC, kc = ch - row * KC;
        *(short8*)(Bs + row * KP + kc * 8) =
            *(const short8*)(Bt + (size_t)(c0 + row) * K + kc * 8);
    }
    __syncthreads();

    float4v acc[4][CF];
    #pragma unroll
    for (int fr = 0; fr < 4; ++fr)
        #pragma unroll
        for (int cf = 0; cf < CF; ++cf)
            acc[fr][cf] = (float4v){0.f, 0.f, 0.f, 0.f};

    const int lr = lane & 15;
    const int lk = (lane >> 4) * 8;
    const int cw = wid * (MSLICE / 4);

    #pragma unroll
    for (int ks = 0; ks < K; ks += 32) {
        short8 af[4], bfr[CF];
        #pragma unroll
        for (int fr = 0; fr < 4; ++fr)
            af[fr] = *(const short8*)(As + (fr * 16 + lr) * KP + ks + lk);
        #pragma unroll
        for (int cf = 0; cf < CF; ++cf)
            bfr[cf] = *(const short8*)(Bs + (cw + cf * 16 + lr) * KP + ks + lk);
        #pragma unroll
        for (int fr = 0; fr < 4; ++fr)
            #pragma unroll
            for (int cf = 0; cf < CF; ++cf)
                acc[fr][cf] = __builtin_amdgcn_mfma_f32_16x16x32_bf16(
                    af[fr], bfr[cf], acc[fr][cf], 0, 0, 0);
    }

    const int rbase = r0 + (lane >> 4) * 4;
    #pragma unroll
    for (int fr = 0; fr < 4; ++fr) {
        #pragma unroll
        for (int cf = 0; cf < CF; ++cf) {
            int col = c0 + cw + cf * 16 + lr;
            #pragma unroll
            for (int j = 0; j < 4; ++j) {
                int row = rbase + fr * 16 + j;
                if (row < N)
                    C[(size_t)row * Mtot + col] = f2bf(acc[fr][cf][j]);
            }
        }
    }
}

// ---------------------------- L2 dots --------------------------------------

__global__ void dots_h1_kernel(const unsigned short* __restrict__ hb,
                               const float* __restrict__ al, const float* __restrict__ ar,
                               float* __restrict__ el, float* __restrict__ er, int N) {
    int wave = (blockIdx.x * blockDim.x + threadIdx.x) >> 6;
    int lane = threadIdx.x & 63;
    if (wave >= N) return;
    unsigned int hu = *(const unsigned int*)(hb + (size_t)wave * 128 + lane * 2);
    float h0 = bf2f(hu & 0xffffu), h1 = bf2f(hu >> 16);
    float2 av = *(const float2*)(al + lane * 2);
    float2 rv = *(const float2*)(ar + lane * 2);
    float pel = h0 * av.x + h1 * av.y;
    float per = h0 * rv.x + h1 * rv.y;
    #pragma unroll
    for (int mask = 1; mask < 64; mask <<= 1) {
        pel += __shfl_xor(pel, mask);
        per += __shfl_xor(per, mask);
    }
    if (lane == 0) {
        el[wave] = pel;
        er[wave] = per;
    }
}

// ---------------------------- agg2 (H=1, D=128) ----------------------------

__global__ __launch_bounds__(256) void agg2_kernel(const unsigned short* __restrict__ hb,
                           const float* __restrict__ el, const float* __restrict__ er,
                           const int* __restrict__ srcs, const int* __restrict__ row_start,
                           const float* __restrict__ bias, float* __restrict__ out, int N) {
    int wave = (blockIdx.x * blockDim.x + threadIdx.x) >> 6;
    int lane = threadIdx.x & 63;
    if (wave >= N) return;
    const int n = wave;
    const int rs = row_start[n];
    const int re = row_start[n + 1];
    const int deg = re - rs;

    float acc0 = 0.f, acc1 = 0.f;

    if (deg > 0) {
        const int cnt0 = deg < 64 ? deg : 64;
        const float ern = er[n];
        int sv = 0;
        float e0 = -INFINITY;
        if (lane < cnt0) {
            sv = srcs[rs + lane];
            e0 = lrelu(el[sv] + ern);
        }
        float m0 = e0;
        for (int base = rs + 64; base < re; base += 64) {  // rare
            int idx = base + lane;
            if (idx < re) m0 = fmaxf(m0, lrelu(el[srcs[idx]] + ern));
        }
        #pragma unroll
        for (int mask = 1; mask < 64; mask <<= 1)
            m0 = fmaxf(m0, __shfl_xor(m0, mask));
        float a0 = __expf(e0 - m0);
        float d0 = a0;
        #pragma unroll
        for (int mask = 1; mask < 64; mask <<= 1)
            d0 += __shfl_xor(d0, mask);
        float dsel = d0;
        int i = 0;
        for (; i + 4 <= cnt0; i += 4) {
            int s0 = __shfl(sv, i), s1 = __shfl(sv, i + 1);
            int s2 = __shfl(sv, i + 2), s3 = __shfl(sv, i + 3);
            float w0 = __shfl(a0, i), w1 = __shfl(a0, i + 1);
            float w2 = __shfl(a0, i + 2), w3 = __shfl(a0, i + 3);
            unsigned int v0 = *(const unsigned int*)(hb + (size_t)s0 * 128 + lane * 2);
            unsigned int v1 = *(const unsigned int*)(hb + (size_t)s1 * 128 + lane * 2);
            unsigned int v2 = *(const unsigned int*)(hb + (size_t)s2 * 128 + lane * 2);
            unsigned int v3 = *(const unsigned int*)(hb + (size_t)s3 * 128 + lane * 2);
            acc0 += w0 * bf2f(v0 & 0xffffu); acc1 += w0 * bf2f(v0 >> 16);
            acc0 += w1 * bf2f(v1 & 0xffffu); acc1 += w1 * bf2f(v1 >> 16);
            acc0 += w2 * bf2f(v2 & 0xffffu); acc1 += w2 * bf2f(v2 >> 16);
            acc0 += w3 * bf2f(v3 & 0xffffu); acc1 += w3 * bf2f(v3 >> 16);
        }
        for (; i < cnt0; ++i) {
            int s0 = __shfl(sv, i);
            float w = __shfl(a0, i);
            unsigned int v = *(const unsigned int*)(hb + (size_t)s0 * 128 + lane * 2);
            acc0 += w * bf2f(v & 0xffffu); acc1 += w * bf2f(v >> 16);
        }
        for (int idx = rs + 64; idx < re; ++idx) {  // rare
            int s = srcs[idx];
            float e = lrelu(el[s] + ern);
            float a_ = __expf(e - m0);
            dsel += a_;
            unsigned int v = *(const unsigned int*)(hb + (size_t)s * 128 + lane * 2);
            acc0 += a_ * bf2f(v & 0xffffu); acc1 += a_ * bf2f(v >> 16);
        }
        float invd = 1.f / dsel;
        acc0 *= invd; acc1 *= invd;
    }
    float o0 = acc0 + bias[lane * 2];
    float o1 = acc1 + bias[lane * 2 + 1];
    *(float2*)(out + (size_t)n * 128 + lane * 2) = make_float2(o0, o1);
}

// ---------------------------------------------------------------------------

extern "C" void kernel_launch(void* const* d_in, const int* in_sizes, int n_in,
                              void* d_out, int out_size, void* d_ws, size_t ws_size,
                              hipStream_t stream) {
    const float* x   = (const float*)d_in[0];
    const int*   src = (const int*)d_in[1];
    const int*   dst = (const int*)d_in[2];
    const float* W1  = (const float*)d_in[3];
    const float* al1 = (const float*)d_in[4];
    const float* ar1 = (const float*)d_in[5];
    const float* b1  = (const float*)d_in[6];
    const float* W2  = (const float*)d_in[7];
    const float* al2 = (const float*)d_in[8];
    const float* ar2 = (const float*)d_in[9];
    const float* b2  = (const float*)d_in[10];
    float* out = (float*)d_out;

    const int N = in_sizes[0] / 128;  // 50000
    const int E = in_sizes[1];        // 800000

    char* ws = (char*)d_ws;
    size_t oXB   = 0;                              // xb bf16 [N*128]        12.8MB
    size_t oA1   = oXB + (size_t)N * 128 * 2;      // A1 bf16 [N*4*128]      51.2MB (h2b aliases)
    size_t oH1R  = oA1 + (size_t)N * 512 * 2;      // h1rb bf16 [N*256]      25.6MB
    size_t oW1th = oH1R + (size_t)N * 256 * 2;     // [4*64*128] bf16
    size_t oQ    = oW1th + 32768 * 2;              // [128*8] f32
    size_t oW2t  = oQ + 1024 * 4;                  // [128*256] bf16
    size_t oEl1  = oW2t + 32768 * 2;               // [N*4] f32
    size_t oEr1  = oEl1 + (size_t)N * 4 * 4;
    size_t oEl2  = oEr1 + (size_t)N * 4 * 4;       // [N] f32
    size_t oEr2  = oEl2 + (size_t)N * 4;
    size_t oCnt  = oEr2 + (size_t)N * 4;
    size_t oFill = oCnt + (size_t)N * 4;
    size_t oRow  = oFill + (size_t)N * 4;
    size_t oBsum = oRow + (((size_t)(N + 1) * 4 + 15) & ~(size_t)15);
    size_t oBoff = oBsum + 256 * 4;
    size_t oSrcs = oBoff + 256 * 4;                // [E]

    unsigned short* xb   = (unsigned short*)(ws + oXB);
    unsigned short* A1   = (unsigned short*)(ws + oA1);
    unsigned short* h2b  = (unsigned short*)(ws + oA1);  // reuse: A1 dead after gemm1h
    unsigned short* h1rb = (unsigned short*)(ws + oH1R);
    unsigned short* w1th = (unsigned short*)(ws + oW1th);
    float*          Qf   = (float*)(ws + oQ);
    unsigned short* w2t  = (unsigned short*)(ws + oW2t);
    float* el1 = (float*)(ws + oEl1);
    float* er1 = (float*)(ws + oEr1);
    float* el2 = (float*)(ws + oEl2);
    float* er2 = (float*)(ws + oEr2);
    int* cnt       = (int*)(ws + oCnt);
    int* fill      = (int*)(ws + oFill);
    int* row_start = (int*)(ws + oRow);
    int* bsum      = (int*)(ws + oBsum);
    int* boff      = (int*)(ws + oBoff);
    int* srcs      = (int*)(ws + oSrcs);

    const int nch = (N + 255) / 256;

    // ---- CSR build (by dst) ----
    hipMemsetAsync(cnt, 0, (size_t)N * 4, stream);
    hist_kernel<<<(E + 255) / 256, 256, 0, stream>>>(dst, cnt, E);
    scan_a_kernel<<<nch, 256, 0, stream>>>(cnt, bsum, N);
    scan_b_kernel<<<1, 256, 0, stream>>>(bsum, boff, nch);
    scan_c_kernel<<<nch, 256, 0, stream>>>(cnt, boff, row_start, N, E);
    hipMemsetAsync(fill, 0, (size_t)N * 4, stream);
    scatter_kernel<<<(E + 255) / 256, 256, 0, stream>>>(src, dst, row_start, fill, srcs, E);

    // ---- prep ----
    wprep_kernel<<<(66560 + 255) / 256, 256, 0, stream>>>(W1, al1, ar1, W2, w1th, Qf, w2t);
    xprep_kernel<<<512, 256, 0, stream>>>(x, Qf, xb, el1, er1, N);

    const int nrowb = (N + 63) / 64;
    const int nwaveb = (N + 3) / 4;

    // ---- layer 1 (x-space aggregation, then per-head GEMM) ----
    agg1x_kernel<<<nwaveb, 256, 0, stream>>>(xb, el1, er1, srcs, row_start, A1, N);
    gemm1h_kernel<<<dim3(nrowb, 1, 4), 256, 0, stream>>>(A1, w1th, b1, h1rb, N);

    // ---- layer 2 ----
    mfma_gemm_kernel<256, 64><<<dim3(nrowb, 2), 256, 0, stream>>>(h1rb, w2t, h2b, N, 128);
    dots_h1_kernel<<<nwaveb, 256, 0, stream>>>(h2b, al2, ar2, el2, er2, N);
    agg2_kernel<<<nwaveb, 256, 0, stream>>>(h2b, el2, er2, srcs, row_start, b2, out, N);
}

// Round 7
// 238.297 us; speedup vs baseline: 1.2298x; 1.2298x over previous
//
#include <hip/hip_runtime.h>
#include <hip/hip_bf16.h>
#include <math.h>

// ---------------------------------------------------------------------------
// GAT 2-layer forward, MI355X.
// R6->R7: aggs were DS(shuffle)-pipe bound (~200 ds_bpermute-class ops/wave
// = 80us floor; byte traffic halved 3x across R3-R6 with zero effect).
// Restructure:
//  - softmax without max-subtraction (exp(e)/sum exp(e) == exp(e-m)/sum; |e|~6)
//  - denominator accumulated per-lane from the broadcast alphas (free)
//  - pass-2 broadcast via LDS table: s_tbl[i] uniform b32 + a_tbl[i] uniform
//    b128 (same-addr broadcast, conflict-free) -> 2 DS ops/edge vs 5 shuffles
//  - el/er dots via MFMA GEMM vs Qt[16][128] (zero shuffles), both layers
// Pipeline: CSR -> wprep(W1th,Qt1,Qt2,W2t) -> xcvt -> dots1(MFMA) ->
//   agg1x(x-space, LDS-table) -> gemm1h -> gemm2 -> dots2(MFMA) -> agg2 -> out
// ---------------------------------------------------------------------------

#define NEG_SLOPE 0.2f

typedef short short8 __attribute__((ext_vector_type(8)));
typedef float float4v __attribute__((ext_vector_type(4)));

static __device__ __forceinline__ float lrelu(float v) {
    return v > 0.f ? v : NEG_SLOPE * v;
}

static __device__ __forceinline__ unsigned short f2bf(float f) {
    unsigned int u = __float_as_uint(f);
    u = (u + 0x7fffu + ((u >> 16) & 1u)) >> 16;
    return (unsigned short)u;
}
static __device__ __forceinline__ float bf2f(unsigned int lo16) {
    return __uint_as_float(lo16 << 16);
}

// ---------------------------- CSR build ------------------------------------

__global__ void hist_kernel(const int* __restrict__ dst, int* __restrict__ cnt, int E) {
    int e = blockIdx.x * blockDim.x + threadIdx.x;
    if (e < E) atomicAdd(&cnt[dst[e]], 1);
}

__global__ void scan_a_kernel(const int* __restrict__ cnt, int* __restrict__ bsum, int N) {
    __shared__ int sdata[256];
    int t = threadIdx.x;
    int i = blockIdx.x * 256 + t;
    sdata[t] = (i < N) ? cnt[i] : 0;
    __syncthreads();
    for (int off = 128; off > 0; off >>= 1) {
        if (t < off) sdata[t] += sdata[t + off];
        __syncthreads();
    }
    if (t == 0) bsum[blockIdx.x] = sdata[0];
}

__global__ void scan_b_kernel(const int* __restrict__ bsum, int* __restrict__ boff, int nch) {
    __shared__ int s[256];
    int t = threadIdx.x;
    int v = (t < nch) ? bsum[t] : 0;
    s[t] = v;
    __syncthreads();
    for (int off = 1; off < 256; off <<= 1) {
        int add = (t >= off) ? s[t - off] : 0;
        __syncthreads();
        s[t] += add;
        __syncthreads();
    }
    boff[t] = s[t] - v;  // exclusive
}

__global__ void scan_c_kernel(const int* __restrict__ cnt, const int* __restrict__ boff,
                              int* __restrict__ row_start, int N, int E) {
    __shared__ int s[256];
    int t = threadIdx.x;
    int i = blockIdx.x * 256 + t;
    int v = (i < N) ? cnt[i] : 0;
    s[t] = v;
    __syncthreads();
    for (int off = 1; off < 256; off <<= 1) {
        int add = (t >= off) ? s[t - off] : 0;
        __syncthreads();
        s[t] += add;
        __syncthreads();
    }
    if (i < N) row_start[i] = s[t] - v + boff[blockIdx.x];
    if (i == N - 1) row_start[N] = E;
}

__global__ void scatter_kernel(const int* __restrict__ src, const int* __restrict__ dst,
                               const int* __restrict__ row_start, int* __restrict__ fill,
                               int* __restrict__ srcs, int E) {
    int e = blockIdx.x * blockDim.x + threadIdx.x;
    if (e < E) {
        int d = dst[e];
        int pos = row_start[d] + atomicAdd(&fill[d], 1);
        srcs[pos] = src[e];
    }
}

// ---------------------------- weight prep ----------------------------------
// W1th[4][64][128] bf16 (per-head transposed W1)
// Qt1[16][128] bf16: rows 0-3 = ql[h] = W1_h @ al1[h]; rows 4-7 = qr[h]; 8-15 zero
// Qt2[16][128] bf16: row 0 = al2, row 1 = ar2, rest zero
// W2t[128][256] bf16 (transposed W2)

__global__ void wprep_kernel(const float* __restrict__ W1, const float* __restrict__ al1,
                             const float* __restrict__ ar1, const float* __restrict__ W2,
                             const float* __restrict__ al2, const float* __restrict__ ar2,
                             unsigned short* __restrict__ W1th, unsigned short* __restrict__ Qt1,
                             unsigned short* __restrict__ Qt2, unsigned short* __restrict__ W2t) {
    int idx = blockIdx.x * 256 + threadIdx.x;
    if (idx < 32768) {                       // W1th
        int h = idx >> 13;
        int r = idx & 8191;
        int d = r >> 7, k = r & 127;
        W1th[idx] = f2bf(W1[k * 256 + h * 64 + d]);
    } else if (idx < 34816) {                // Qt1
        int j = idx - 32768;
        int c = j >> 7, k = j & 127;
        float s = 0.f;
        if (c < 8) {
            int h = c & 3;
            const float* av = ((c < 4) ? al1 : ar1) + h * 64;
            const float* wrow = W1 + k * 256 + h * 64;
            #pragma unroll 8
            for (int d = 0; d < 64; ++d) s += wrow[d] * av[d];
        }
        Qt1[j] = f2bf(s);
    } else if (idx < 36864) {                // Qt2
        int j = idx - 34816;
        int c = j >> 7, k = j & 127;
        float s = (c == 0) ? al2[k] : (c == 1) ? ar2[k] : 0.f;
        Qt2[j] = f2bf(s);
    } else if (idx < 69632) {                // W2t
        int j = idx - 36864;
        int m = j >> 8, k = j & 255;
        W2t[(size_t)m * 256 + k] = f2bf(W2[(size_t)k * 128 + m]);
    }
}

// ---------------------------- x convert ------------------------------------

__global__ void xcvt_kernel(const float* __restrict__ X, unsigned short* __restrict__ Xb,
                            int total8) {
    int idx = blockIdx.x * 256 + threadIdx.x;
    if (idx < total8) {
        float4 a = ((const float4*)X)[idx * 2];
        float4 b = ((const float4*)X)[idx * 2 + 1];
        ushort4 o1, o2;
        o1.x = f2bf(a.x); o1.y = f2bf(a.y); o1.z = f2bf(a.z); o1.w = f2bf(a.w);
        o2.x = f2bf(b.x); o2.y = f2bf(b.y); o2.z = f2bf(b.z); o2.w = f2bf(b.w);
        ((ushort4*)Xb)[idx * 2] = o1;
        ((ushort4*)Xb)[idx * 2 + 1] = o2;
    }
}

// ---------------------------- dots via MFMA --------------------------------
// el[n][0..C), er[n][0..C) = hb[n][0..128) @ Qt[16][128] (cols 0..C-1 = el,
// C..2C-1 = er). One 64-row block, 4 waves x 16 rows, K=128 in LDS.

template <int C>
__global__ __launch_bounds__(256) void dots_mfma_kernel(
        const unsigned short* __restrict__ hb,   // [N][128] bf16
        const unsigned short* __restrict__ Qt,   // [16][128] bf16
        float* __restrict__ el, float* __restrict__ er, int N) {
    constexpr int KP = 136;
    __shared__ unsigned short As[64 * KP];
    __shared__ unsigned short Bs[16 * KP];
    const int tid = threadIdx.x;
    const int wid = tid >> 6, lane = tid & 63;
    const int r0 = blockIdx.x * 64;
    for (int ch = tid; ch < 64 * 16; ch += 256) {
        int row = ch >> 4, kc = ch & 15;
        int gr = r0 + row;
        short8 v = {};
        if (gr < N) v = *(const short8*)(hb + (size_t)gr * 128 + kc * 8);
        *(short8*)(As + row * KP + kc * 8) = v;
    }
    {   // exactly 256 chunks
        int row = tid >> 4, kc = tid & 15;
        *(short8*)(Bs + row * KP + kc * 8) = *(const short8*)(Qt + row * 128 + kc * 8);
    }
    __syncthreads();
    float4v acc = (float4v){0.f, 0.f, 0.f, 0.f};
    const int lr = lane & 15, lk = (lane >> 4) * 8;
    #pragma unroll
    for (int ks = 0; ks < 128; ks += 32) {
        short8 af = *(const short8*)(As + (wid * 16 + lr) * KP + ks + lk);
        short8 bf_ = *(const short8*)(Bs + lr * KP + ks + lk);
        acc = __builtin_amdgcn_mfma_f32_16x16x32_bf16(af, bf_, acc, 0, 0, 0);
    }
    const int rbase = r0 + wid * 16 + (lane >> 4) * 4;
    #pragma unroll
    for (int j = 0; j < 4; ++j) {
        int row = rbase + j;
        if (row < N) {
            if (lr < C) el[(size_t)row * C + lr] = acc[j];
            else if (lr < 2 * C) er[(size_t)row * C + (lr - C)] = acc[j];
        }
    }
}

// ---------------------------- agg1 in x-space (LDS-table) ------------------
// One wave per dst node. Stage (s, alpha[4]) per edge in LDS once; pass 2
// reads via uniform-address broadcast (1 b32 + 1 b128 per edge). No max
// subtraction (|e| ~ 6 << 88); denominator accumulated per-lane (free).

__global__ __launch_bounds__(256) void agg1x_kernel(const unsigned short* __restrict__ xb,
                            const float* __restrict__ el, const float* __restrict__ er,
                            const int* __restrict__ srcs, const int* __restrict__ row_start,
                            unsigned short* __restrict__ A1, int N) {
    __shared__ int   s_tbl[4][64];
    __shared__ float a_tbl[4][64][4];
    const int wslot = threadIdx.x >> 6;
    const int lane = threadIdx.x & 63;
    const int n = (blockIdx.x * 256 + threadIdx.x) >> 6;
    if (n >= N) return;
    const int rs = row_start[n];
    const int re = row_start[n + 1];

    float acc[8];
    #pragma unroll
    for (int j = 0; j < 8; ++j) acc[j] = 0.f;
    float d0 = 0.f, d1 = 0.f, d2 = 0.f, d3 = 0.f;

    if (re > rs) {
        const float4 ern = *(const float4*)(er + (size_t)n * 4);
        for (int base = rs; base < re; base += 64) {
            const int cnt = (re - base) < 64 ? (re - base) : 64;
            // drain pending table reads (prev chunk) before overwrite
            asm volatile("s_waitcnt lgkmcnt(0)" ::: "memory");
            if (lane < cnt) {
                int sv = srcs[base + lane];
                float4 ev = *(const float4*)(el + (size_t)sv * 4);
                float4 av;
                av.x = __expf(lrelu(ev.x + ern.x));
                av.y = __expf(lrelu(ev.y + ern.y));
                av.z = __expf(lrelu(ev.z + ern.z));
                av.w = __expf(lrelu(ev.w + ern.w));
                s_tbl[wslot][lane] = sv;
                *(float4*)&a_tbl[wslot][lane][0] = av;
            }
            asm volatile("s_waitcnt lgkmcnt(0)" ::: "memory");
            int i = 0;
            for (; i + 4 <= cnt; i += 4) {
                int s0 = s_tbl[wslot][i],     s1 = s_tbl[wslot][i + 1];
                int s2 = s_tbl[wslot][i + 2], s3 = s_tbl[wslot][i + 3];
                float4 w0 = *(const float4*)&a_tbl[wslot][i][0];
                float4 w1 = *(const float4*)&a_tbl[wslot][i + 1][0];
                float4 w2 = *(const float4*)&a_tbl[wslot][i + 2][0];
                float4 w3 = *(const float4*)&a_tbl[wslot][i + 3][0];
                unsigned int v0 = *(const unsigned int*)(xb + (size_t)s0 * 128 + lane * 2);
                unsigned int v1 = *(const unsigned int*)(xb + (size_t)s1 * 128 + lane * 2);
                unsigned int v2 = *(const unsigned int*)(xb + (size_t)s2 * 128 + lane * 2);
                unsigned int v3 = *(const unsigned int*)(xb + (size_t)s3 * 128 + lane * 2);
                d0 += w0.x + w1.x + w2.x + w3.x;
                d1 += w0.y + w1.y + w2.y + w3.y;
                d2 += w0.z + w1.z + w2.z + w3.z;
                d3 += w0.w + w1.w + w2.w + w3.w;
                float x00 = bf2f(v0 & 0xffffu), x01 = bf2f(v0 >> 16);
                float x10 = bf2f(v1 & 0xffffu), x11 = bf2f(v1 >> 16);
                float x20 = bf2f(v2 & 0xffffu), x21 = bf2f(v2 >> 16);
                float x30 = bf2f(v3 & 0xffffu), x31 = bf2f(v3 >> 16);
                acc[0] += w0.x * x00 + w1.x * x10 + w2.x * x20 + w3.x * x30;
                acc[1] += w0.x * x01 + w1.x * x11 + w2.x * x21 + w3.x * x31;
                acc[2] += w0.y * x00 + w1.y * x10 + w2.y * x20 + w3.y * x30;
                acc[3] += w0.y * x01 + w1.y * x11 + w2.y * x21 + w3.y * x31;
                acc[4] += w0.z * x00 + w1.z * x10 + w2.z * x20 + w3.z * x30;
                acc[5] += w0.z * x01 + w1.z * x11 + w2.z * x21 + w3.z * x31;
                acc[6] += w0.w * x00 + w1.w * x10 + w2.w * x20 + w3.w * x30;
                acc[7] += w0.w * x01 + w1.w * x11 + w2.w * x21 + w3.w * x31;
            }
            for (; i < cnt; ++i) {
                int s0 = s_tbl[wslot][i];
                float4 w = *(const float4*)&a_tbl[wslot][i][0];
                unsigned int v = *(const unsigned int*)(xb + (size_t)s0 * 128 + lane * 2);
                d0 += w.x; d1 += w.y; d2 += w.z; d3 += w.w;
                float x0 = bf2f(v & 0xffffu), x1 = bf2f(v >> 16);
                acc[0] += w.x * x0; acc[1] += w.x * x1;
                acc[2] += w.y * x0; acc[3] += w.y * x1;
                acc[4] += w.z * x0; acc[5] += w.z * x1;
                acc[6] += w.w * x0; acc[7] += w.w * x1;
            }
        }
        float i0 = 1.f / d0, i1 = 1.f / d1, i2 = 1.f / d2, i3 = 1.f / d3;
        acc[0] *= i0; acc[1] *= i0;
        acc[2] *= i1; acc[3] *= i1;
        acc[4] *= i2; acc[5] *= i2;
        acc[6] *= i3; acc[7] *= i3;
    }
    #pragma unroll
    for (int h = 0; h < 4; ++h) {
        unsigned int pk = (unsigned int)f2bf(acc[h * 2]) |
                          ((unsigned int)f2bf(acc[h * 2 + 1]) << 16);
        *(unsigned int*)(A1 + (size_t)n * 512 + h * 128 + lane * 2) = pk;
    }
}

// ---------------------------- per-head GEMM1 (bf16 MFMA) -------------------

__global__ __launch_bounds__(256) void gemm1h_kernel(
        const unsigned short* __restrict__ A1,    // [N][4][128] bf16
        const unsigned short* __restrict__ W1th,  // [4][64][128] bf16
        const float* __restrict__ b1,             // [256] f32
        unsigned short* __restrict__ h1rb,        // [N][256] bf16
        int N) {
    constexpr int KP = 136;
    __shared__ unsigned short As[64 * KP];
    __shared__ unsigned short Bs[64 * KP];
    const int tid = threadIdx.x;
    const int wid = tid >> 6;
    const int lane = tid & 63;
    const int r0 = blockIdx.x * 64;
    const int h = blockIdx.z;

    for (int ch = tid; ch < 64 * 16; ch += 256) {
        int row = ch >> 4, kc = ch & 15;
        int gr = r0 + row;
        short8 v = {};
        if (gr < N) v = *(const short8*)(A1 + (size_t)gr * 512 + h * 128 + kc * 8);
        *(short8*)(As + row * KP + kc * 8) = v;
    }
    for (int ch = tid; ch < 64 * 16; ch += 256) {
        int row = ch >> 4, kc = ch & 15;
        *(short8*)(Bs + row * KP + kc * 8) =
            *(const short8*)(W1th + (size_t)h * 8192 + row * 128 + kc * 8);
    }
    __syncthreads();

    float4v acc[4];
    #pragma unroll
    for (int fr = 0; fr < 4; ++fr) acc[fr] = (float4v){0.f, 0.f, 0.f, 0.f};

    const int lr = lane & 15;
    const int lk = (lane >> 4) * 8;
    const int cw = wid * 16;

    #pragma unroll
    for (int ks = 0; ks < 128; ks += 32) {
        short8 bfr = *(const short8*)(Bs + (cw + lr) * KP + ks + lk);
        #pragma unroll
        for (int fr = 0; fr < 4; ++fr) {
            short8 af = *(const short8*)(As + (fr * 16 + lr) * KP + ks + lk);
            acc[fr] = __builtin_amdgcn_mfma_f32_16x16x32_bf16(af, bfr, acc[fr], 0, 0, 0);
        }
    }

    const int col = h * 64 + cw + lr;
    const float bias = b1[col];
    const int rbase = r0 + (lane >> 4) * 4;
    #pragma unroll
    for (int fr = 0; fr < 4; ++fr) {
        #pragma unroll
        for (int j = 0; j < 4; ++j) {
            int row = rbase + fr * 16 + j;
            if (row < N)
                h1rb[(size_t)row * 256 + col] = f2bf(fmaxf(acc[fr][j] + bias, 0.f));
        }
    }
}

// ---------------------------- GEMM2 (bf16 MFMA) ----------------------------

template <int K, int MSLICE>
__global__ __launch_bounds__(256) void mfma_gemm_kernel(
        const unsigned short* __restrict__ A,   // [N][K] bf16
        const unsigned short* __restrict__ Bt,  // [Mtot][K] bf16
        unsigned short* __restrict__ C,         // [N][Mtot] bf16
        int N, int Mtot) {
    constexpr int KP = K + 8;
    constexpr int CF = MSLICE / 64;
    constexpr int KC = K / 8;
    __shared__ unsigned short As[64 * KP];
    __shared__ unsigned short Bs[MSLICE * KP];
    const int tid = threadIdx.x;
    const int wid = tid >> 6;
    const int lane = tid & 63;
    const int r0 = blockIdx.x * 64;
    const int c0 = blockIdx.y * MSLICE;

    for (int ch = tid; ch < 64 * KC; ch += 256) {
        int row = ch / KC, kc = ch - row * KC;
        int gr = r0 + row;
        short8 v = {};
        if (gr < N) v = *(const short8*)(A + (size_t)gr * K + kc * 8);
        *(short8*)(As + row * KP + kc * 8) = v;
    }
    for (int ch = tid; ch < MSLICE * KC; ch += 256) {
        int row = ch / KC, kc = ch - row * KC;
        *(short8*)(Bs + row * KP + kc * 8) =
            *(const short8*)(Bt + (size_t)(c0 + row) * K + kc * 8);
    }
    __syncthreads();

    float4v acc[4][CF];
    #pragma unroll
    for (int fr = 0; fr < 4; ++fr)
        #pragma unroll
        for (int cf = 0; cf < CF; ++cf)
            acc[fr][cf] = (float4v){0.f, 0.f, 0.f, 0.f};

    const int lr = lane & 15;
    const int lk = (lane >> 4) * 8;
    const int cw = wid * (MSLICE / 4);

    #pragma unroll
    for (int ks = 0; ks < K; ks += 32) {
        short8 af[4], bfr[CF];
        #pragma unroll
        for (int fr = 0; fr < 4; ++fr)
            af[fr] = *(const short8*)(As + (fr * 16 + lr) * KP + ks + lk);
        #pragma unroll
        for (int cf = 0; cf < CF; ++cf)
            bfr[cf] = *(const short8*)(Bs + (cw + cf * 16 + lr) * KP + ks + lk);
        #pragma unroll
        for (int fr = 0; fr < 4; ++fr)
            #pragma unroll
            for (int cf = 0; cf < CF; ++cf)
                acc[fr][cf] = __builtin_amdgcn_mfma_f32_16x16x32_bf16(
                    af[fr], bfr[cf], acc[fr][cf], 0, 0, 0);
    }

    const int rbase = r0 + (lane >> 4) * 4;
    #pragma unroll
    for (int fr = 0; fr < 4; ++fr) {
        #pragma unroll
        for (int cf = 0; cf < CF; ++cf) {
            int col = c0 + cw + cf * 16 + lr;
            #pragma unroll
            for (int j = 0; j < 4; ++j) {
                int row = rbase + fr * 16 + j;
                if (row < N)
                    C[(size_t)row * Mtot + col] = f2bf(acc[fr][cf][j]);
            }
        }
    }
}

// ---------------------------- agg2 (H=1, D=128, LDS-table) -----------------

__global__ __launch_bounds__(256) void agg2_kernel(const unsigned short* __restrict__ hb,
                           const float* __restrict__ el, const float* __restrict__ er,
                           const int* __restrict__ srcs, const int* __restrict__ row_start,
                           const float* __restrict__ bias, float* __restrict__ out, int N) {
    __shared__ uint2 t_tbl[4][64];
    const int wslot = threadIdx.x >> 6;
    const int lane = threadIdx.x & 63;
    const int n = (blockIdx.x * 256 + threadIdx.x) >> 6;
    if (n >= N) return;
    const int rs = row_start[n];
    const int re = row_start[n + 1];

    float acc0 = 0.f, acc1 = 0.f, d = 0.f;

    if (re > rs) {
        const float ern = er[n];
        for (int base = rs; base < re; base += 64) {
            const int cnt = (re - base) < 64 ? (re - base) : 64;
            asm volatile("s_waitcnt lgkmcnt(0)" ::: "memory");
            if (lane < cnt) {
                int sv = srcs[base + lane];
                float a = __expf(lrelu(el[sv] + ern));
                t_tbl[wslot][lane] = make_uint2((unsigned int)sv, __float_as_uint(a));
            }
            asm volatile("s_waitcnt lgkmcnt(0)" ::: "memory");
            int i = 0;
            for (; i + 4 <= cnt; i += 4) {
                uint2 t0 = t_tbl[wslot][i],     t1 = t_tbl[wslot][i + 1];
                uint2 t2 = t_tbl[wslot][i + 2], t3 = t_tbl[wslot][i + 3];
                float w0 = __uint_as_float(t0.y), w1 = __uint_as_float(t1.y);
                float w2 = __uint_as_float(t2.y), w3 = __uint_as_float(t3.y);
                unsigned int v0 = *(const unsigned int*)(hb + (size_t)t0.x * 128 + lane * 2);
                unsigned int v1 = *(const unsigned int*)(hb + (size_t)t1.x * 128 + lane * 2);
                unsigned int v2 = *(const unsigned int*)(hb + (size_t)t2.x * 128 + lane * 2);
                unsigned int v3 = *(const unsigned int*)(hb + (size_t)t3.x * 128 + lane * 2);
                d += w0 + w1 + w2 + w3;
                acc0 += w0 * bf2f(v0 & 0xffffu) + w1 * bf2f(v1 & 0xffffu) +
                        w2 * bf2f(v2 & 0xffffu) + w3 * bf2f(v3 & 0xffffu);
                acc1 += w0 * bf2f(v0 >> 16) + w1 * bf2f(v1 >> 16) +
                        w2 * bf2f(v2 >> 16) + w3 * bf2f(v3 >> 16);
            }
            for (; i < cnt; ++i) {
                uint2 t = t_tbl[wslot][i];
                float w = __uint_as_float(t.y);
                unsigned int v = *(const unsigned int*)(hb + (size_t)t.x * 128 + lane * 2);
                d += w;
                acc0 += w * bf2f(v & 0xffffu);
                acc1 += w * bf2f(v >> 16);
            }
        }
        float invd = 1.f / d;
        acc0 *= invd; acc1 *= invd;
    }
    float o0 = acc0 + bias[lane * 2];
    float o1 = acc1 + bias[lane * 2 + 1];
    *(float2*)(out + (size_t)n * 128 + lane * 2) = make_float2(o0, o1);
}

// ---------------------------------------------------------------------------

extern "C" void kernel_launch(void* const* d_in, const int* in_sizes, int n_in,
                              void* d_out, int out_size, void* d_ws, size_t ws_size,
                              hipStream_t stream) {
    const float* x   = (const float*)d_in[0];
    const int*   src = (const int*)d_in[1];
    const int*   dst = (const int*)d_in[2];
    const float* W1  = (const float*)d_in[3];
    const float* al1 = (const float*)d_in[4];
    const float* ar1 = (const float*)d_in[5];
    const float* b1  = (const float*)d_in[6];
    const float* W2  = (const float*)d_in[7];
    const float* al2 = (const float*)d_in[8];
    const float* ar2 = (const float*)d_in[9];
    const float* b2  = (const float*)d_in[10];
    float* out = (float*)d_out;

    const int N = in_sizes[0] / 128;  // 50000
    const int E = in_sizes[1];        // 800000

    char* ws = (char*)d_ws;
    size_t oXB   = 0;                              // xb bf16 [N*128]
    size_t oA1   = oXB + (size_t)N * 128 * 2;      // A1 bf16 [N*4*128] (h2b aliases)
    size_t oH1R  = oA1 + (size_t)N * 512 * 2;      // h1rb bf16 [N*256]
    size_t oW1th = oH1R + (size_t)N * 256 * 2;     // [4*64*128] bf16
    size_t oQt1  = oW1th + 32768 * 2;              // [16*128] bf16
    size_t oQt2  = oQt1 + 2048 * 2;                // [16*128] bf16
    size_t oW2t  = oQt2 + 2048 * 2;                // [128*256] bf16
    size_t oEl1  = oW2t + 32768 * 2;               // [N*4] f32
    size_t oEr1  = oEl1 + (size_t)N * 4 * 4;
    size_t oEl2  = oEr1 + (size_t)N * 4 * 4;       // [N] f32
    size_t oEr2  = oEl2 + (size_t)N * 4;
    size_t oCnt  = oEr2 + (size_t)N * 4;
    size_t oFill = oCnt + (size_t)N * 4;
    size_t oRow  = oFill + (size_t)N * 4;
    size_t oBsum = oRow + (((size_t)(N + 1) * 4 + 15) & ~(size_t)15);
    size_t oBoff = oBsum + 256 * 4;
    size_t oSrcs = oBoff + 256 * 4;                // [E]

    unsigned short* xb   = (unsigned short*)(ws + oXB);
    unsigned short* A1   = (unsigned short*)(ws + oA1);
    unsigned short* h2b  = (unsigned short*)(ws + oA1);  // reuse: A1 dead after gemm1h
    unsigned short* h1rb = (unsigned short*)(ws + oH1R);
    unsigned short* w1th = (unsigned short*)(ws + oW1th);
    unsigned short* qt1  = (unsigned short*)(ws + oQt1);
    unsigned short* qt2  = (unsigned short*)(ws + oQt2);
    unsigned short* w2t  = (unsigned short*)(ws + oW2t);
    float* el1 = (float*)(ws + oEl1);
    float* er1 = (float*)(ws + oEr1);
    float* el2 = (float*)(ws + oEl2);
    float* er2 = (float*)(ws + oEr2);
    int* cnt       = (int*)(ws + oCnt);
    int* fill      = (int*)(ws + oFill);
    int* row_start = (int*)(ws + oRow);
    int* bsum      = (int*)(ws + oBsum);
    int* boff      = (int*)(ws + oBoff);
    int* srcs      = (int*)(ws + oSrcs);

    const int nch = (N + 255) / 256;

    // ---- CSR build (by dst) ----
    hipMemsetAsync(cnt, 0, (size_t)N * 4, stream);
    hist_kernel<<<(E + 255) / 256, 256, 0, stream>>>(dst, cnt, E);
    scan_a_kernel<<<nch, 256, 0, stream>>>(cnt, bsum, N);
    scan_b_kernel<<<1, 256, 0, stream>>>(bsum, boff, nch);
    scan_c_kernel<<<nch, 256, 0, stream>>>(cnt, boff, row_start, N, E);
    hipMemsetAsync(fill, 0, (size_t)N * 4, stream);
    scatter_kernel<<<(E + 255) / 256, 256, 0, stream>>>(src, dst, row_start, fill, srcs, E);

    // ---- prep ----
    wprep_kernel<<<(69632 + 255) / 256, 256, 0, stream>>>(W1, al1, ar1, W2, al2, ar2,
                                                          w1th, qt1, qt2, w2t);
    const int x8 = N * 128 / 8;
    xcvt_kernel<<<(x8 + 255) / 256, 256, 0, stream>>>(x, xb, x8);

    const int nrowb = (N + 63) / 64;
    const int nwaveb = (N + 3) / 4;

    // ---- layer 1 ----
    dots_mfma_kernel<4><<<nrowb, 256, 0, stream>>>(xb, qt1, el1, er1, N);
    agg1x_kernel<<<nwaveb, 256, 0, stream>>>(xb, el1, er1, srcs, row_start, A1, N);
    gemm1h_kernel<<<dim3(nrowb, 1, 4), 256, 0, stream>>>(A1, w1th, b1, h1rb, N);

    // ---- layer 2 ----
    mfma_gemm_kernel<256, 64><<<dim3(nrowb, 2), 256, 0, stream>>>(h1rb, w2t, h2b, N, 128);
    dots_mfma_kernel<1><<<nrowb, 256, 0, stream>>>(h2b, qt2, el2, er2, N);
    agg2_kernel<<<nwaveb, 256, 0, stream>>>(h2b, el2, er2, srcs, row_start, b2, out, N);
}

// Round 8
// 235.077 us; speedup vs baseline: 1.2467x; 1.0137x over previous
//
#include <hip/hip_runtime.h>
#include <hip/hip_bf16.h>
#include <math.h>

// ---------------------------------------------------------------------------
// GAT 2-layer forward, MI355X.
// R7->R8:
//  - agg1x hot loop -> packed fp32 (v_pk_fma_f32/v_pk_add_f32): heads pair
//    naturally from a_tbl float4; 8 FMA + 4 add -> 4 pk_fma + 2 pk_add.
//  - launches 15->11: xcvt fused into dots1 (xdots); scan_b folded into
//    scan_c; hist+wprep merged; one memset over cnt+fill.
//  - gemm1h: 128 rows/block (halves W1th re-reads).
// Pipeline: memset -> histwprep -> scan_a -> scan_c' -> scatter -> xdots ->
//   agg1x -> gemm1h -> gemm2 -> dots2 -> agg2
// ---------------------------------------------------------------------------

#define NEG_SLOPE 0.2f

typedef short short8 __attribute__((ext_vector_type(8)));
typedef float float4v __attribute__((ext_vector_type(4)));
typedef float float2v __attribute__((ext_vector_type(2)));

static __device__ __forceinline__ float lrelu(float v) {
    return v > 0.f ? v : NEG_SLOPE * v;
}

static __device__ __forceinline__ unsigned short f2bf(float f) {
    unsigned int u = __float_as_uint(f);
    u = (u + 0x7fffu + ((u >> 16) & 1u)) >> 16;
    return (unsigned short)u;
}
static __device__ __forceinline__ float bf2f(unsigned int lo16) {
    return __uint_as_float(lo16 << 16);
}

// packed step: accP[d][p] (+= w_pair * x_d_broadcast), dP[p] += w_pair
static __device__ __forceinline__ void pk_step(float2v& a00, float2v& a01,
                                               float2v& a10, float2v& a11,
                                               float2v& d0, float2v& d1,
                                               float4 w, unsigned int v) {
    float2v w01; w01[0] = w.x; w01[1] = w.y;
    float2v w23; w23[0] = w.z; w23[1] = w.w;
    float x0 = __uint_as_float(v << 16);
    float x1 = __uint_as_float(v & 0xffff0000u);
    float2v xx0 = {x0, x0};
    float2v xx1 = {x1, x1};
    asm("v_pk_fma_f32 %0, %1, %2, %0" : "+v"(a00) : "v"(w01), "v"(xx0));
    asm("v_pk_fma_f32 %0, %1, %2, %0" : "+v"(a01) : "v"(w23), "v"(xx0));
    asm("v_pk_fma_f32 %0, %1, %2, %0" : "+v"(a10) : "v"(w01), "v"(xx1));
    asm("v_pk_fma_f32 %0, %1, %2, %0" : "+v"(a11) : "v"(w23), "v"(xx1));
    asm("v_pk_add_f32 %0, %1, %0" : "+v"(d0) : "v"(w01));
    asm("v_pk_add_f32 %0, %1, %0" : "+v"(d1) : "v"(w23));
}

// ---------------------------- CSR build ------------------------------------

// merged: hist (blocks [0,nhistblk)) + weight prep (blocks [nhistblk,...))
__global__ void histwprep_kernel(const int* __restrict__ dst, int* __restrict__ cnt,
                                 int E, int nhistblk,
                                 const float* __restrict__ W1, const float* __restrict__ al1,
                                 const float* __restrict__ ar1, const float* __restrict__ W2,
                                 const float* __restrict__ al2, const float* __restrict__ ar2,
                                 unsigned short* __restrict__ W1th, unsigned short* __restrict__ Qt1,
                                 unsigned short* __restrict__ Qt2, unsigned short* __restrict__ W2t) {
    int b = blockIdx.x;
    if (b < nhistblk) {
        int e = b * 256 + threadIdx.x;
        if (e < E) atomicAdd(&cnt[dst[e]], 1);
        return;
    }
    int idx = (b - nhistblk) * 256 + threadIdx.x;
    if (idx < 32768) {                       // W1th [4][64][128]
        int h = idx >> 13;
        int r = idx & 8191;
        int d = r >> 7, k = r & 127;
        W1th[idx] = f2bf(W1[k * 256 + h * 64 + d]);
    } else if (idx < 34816) {                // Qt1 [16][128]
        int j = idx - 32768;
        int c = j >> 7, k = j & 127;
        float s = 0.f;
        if (c < 8) {
            int h = c & 3;
            const float* av = ((c < 4) ? al1 : ar1) + h * 64;
            const float* wrow = W1 + k * 256 + h * 64;
            #pragma unroll 8
            for (int d = 0; d < 64; ++d) s += wrow[d] * av[d];
        }
        Qt1[j] = f2bf(s);
    } else if (idx < 36864) {                // Qt2 [16][128]
        int j = idx - 34816;
        int c = j >> 7, k = j & 127;
        float s = (c == 0) ? al2[k] : (c == 1) ? ar2[k] : 0.f;
        Qt2[j] = f2bf(s);
    } else if (idx < 69632) {                // W2t [128][256]
        int j = idx - 36864;
        int m = j >> 8, k = j & 255;
        W2t[(size_t)m * 256 + k] = f2bf(W2[(size_t)k * 128 + m]);
    }
}

__global__ void scan_a_kernel(const int* __restrict__ cnt, int* __restrict__ bsum, int N) {
    __shared__ int sdata[256];
    int t = threadIdx.x;
    int i = blockIdx.x * 256 + t;
    sdata[t] = (i < N) ? cnt[i] : 0;
    __syncthreads();
    for (int off = 128; off > 0; off >>= 1) {
        if (t < off) sdata[t] += sdata[t + off];
        __syncthreads();
    }
    if (t == 0) bsum[blockIdx.x] = sdata[0];
}

// scan_c with scan_b folded in: each block scans bsum locally for its offset
__global__ void scan_c_kernel(const int* __restrict__ cnt, const int* __restrict__ bsum,
                              int* __restrict__ row_start, int N, int E, int nch) {
    __shared__ int s[256];
    __shared__ int boS;
    int t = threadIdx.x;
    // phase 1: exclusive prefix of bsum at blockIdx.x
    int bv = (t < nch) ? bsum[t] : 0;
    s[t] = bv;
    __syncthreads();
    for (int off = 1; off < 256; off <<= 1) {
        int add = (t >= off) ? s[t - off] : 0;
        __syncthreads();
        s[t] += add;
        __syncthreads();
    }
    if (t == blockIdx.x) boS = s[t] - bv;
    __syncthreads();
    int bo = boS;
    __syncthreads();
    // phase 2: local inclusive scan of cnt
    int i = blockIdx.x * 256 + t;
    int v = (i < N) ? cnt[i] : 0;
    s[t] = v;
    __syncthreads();
    for (int off = 1; off < 256; off <<= 1) {
        int add = (t >= off) ? s[t - off] : 0;
        __syncthreads();
        s[t] += add;
        __syncthreads();
    }
    if (i < N) row_start[i] = s[t] - v + bo;
    if (i == N - 1) row_start[N] = E;
}

__global__ void scatter_kernel(const int* __restrict__ src, const int* __restrict__ dst,
                               const int* __restrict__ row_start, int* __restrict__ fill,
                               int* __restrict__ srcs, int E) {
    int e = blockIdx.x * blockDim.x + threadIdx.x;
    if (e < E) {
        int d = dst[e];
        int pos = row_start[d] + atomicAdd(&fill[d], 1);
        srcs[pos] = src[e];
    }
}

// ---------------------------- xdots: x->bf16 + L1 dots (MFMA) --------------
// Reads x f32, converts, writes xb AND stages LDS; MFMA vs Qt1 -> el1, er1.

__global__ __launch_bounds__(256) void xdots_kernel(
        const float* __restrict__ x, const unsigned short* __restrict__ Qt,
        unsigned short* __restrict__ xb,
        float* __restrict__ el, float* __restrict__ er, int N) {
    constexpr int KP = 136;
    __shared__ unsigned short As[64 * KP];
    __shared__ unsigned short Bs[16 * KP];
    const int tid = threadIdx.x;
    const int wid = tid >> 6, lane = tid & 63;
    const int r0 = blockIdx.x * 64;
    for (int ch = tid; ch < 64 * 16; ch += 256) {
        int row = ch >> 4, kc = ch & 15;
        int gr = r0 + row;
        short8 v = {};
        if (gr < N) {
            float4 a = *(const float4*)(x + (size_t)gr * 128 + kc * 8);
            float4 b = *(const float4*)(x + (size_t)gr * 128 + kc * 8 + 4);
            v[0] = (short)f2bf(a.x); v[1] = (short)f2bf(a.y);
            v[2] = (short)f2bf(a.z); v[3] = (short)f2bf(a.w);
            v[4] = (short)f2bf(b.x); v[5] = (short)f2bf(b.y);
            v[6] = (short)f2bf(b.z); v[7] = (short)f2bf(b.w);
            *(short8*)(xb + (size_t)gr * 128 + kc * 8) = v;
        }
        *(short8*)(As + row * KP + kc * 8) = v;
    }
    {
        int row = tid >> 4, kc = tid & 15;
        *(short8*)(Bs + row * KP + kc * 8) = *(const short8*)(Qt + row * 128 + kc * 8);
    }
    __syncthreads();
    float4v acc = (float4v){0.f, 0.f, 0.f, 0.f};
    const int lr = lane & 15, lk = (lane >> 4) * 8;
    #pragma unroll
    for (int ks = 0; ks < 128; ks += 32) {
        short8 af = *(const short8*)(As + (wid * 16 + lr) * KP + ks + lk);
        short8 bf_ = *(const short8*)(Bs + lr * KP + ks + lk);
        acc = __builtin_amdgcn_mfma_f32_16x16x32_bf16(af, bf_, acc, 0, 0, 0);
    }
    const int rbase = r0 + wid * 16 + (lane >> 4) * 4;
    #pragma unroll
    for (int j = 0; j < 4; ++j) {
        int row = rbase + j;
        if (row < N) {
            if (lr < 4) el[(size_t)row * 4 + lr] = acc[j];
            else if (lr < 8) er[(size_t)row * 4 + (lr - 4)] = acc[j];
        }
    }
}

// ---------------------------- L2 dots (MFMA) -------------------------------

__global__ __launch_bounds__(256) void dots2_kernel(
        const unsigned short* __restrict__ hb, const unsigned short* __restrict__ Qt,
        float* __restrict__ el, float* __restrict__ er, int N) {
    constexpr int KP = 136;
    __shared__ unsigned short As[64 * KP];
    __shared__ unsigned short Bs[16 * KP];
    const int tid = threadIdx.x;
    const int wid = tid >> 6, lane = tid & 63;
    const int r0 = blockIdx.x * 64;
    for (int ch = tid; ch < 64 * 16; ch += 256) {
        int row = ch >> 4, kc = ch & 15;
        int gr = r0 + row;
        short8 v = {};
        if (gr < N) v = *(const short8*)(hb + (size_t)gr * 128 + kc * 8);
        *(short8*)(As + row * KP + kc * 8) = v;
    }
    {
        int row = tid >> 4, kc = tid & 15;
        *(short8*)(Bs + row * KP + kc * 8) = *(const short8*)(Qt + row * 128 + kc * 8);
    }
    __syncthreads();
    float4v acc = (float4v){0.f, 0.f, 0.f, 0.f};
    const int lr = lane & 15, lk = (lane >> 4) * 8;
    #pragma unroll
    for (int ks = 0; ks < 128; ks += 32) {
        short8 af = *(const short8*)(As + (wid * 16 + lr) * KP + ks + lk);
        short8 bf_ = *(const short8*)(Bs + lr * KP + ks + lk);
        acc = __builtin_amdgcn_mfma_f32_16x16x32_bf16(af, bf_, acc, 0, 0, 0);
    }
    const int rbase = r0 + wid * 16 + (lane >> 4) * 4;
    #pragma unroll
    for (int j = 0; j < 4; ++j) {
        int row = rbase + j;
        if (row < N) {
            if (lr == 0) el[row] = acc[j];
            else if (lr == 1) er[row] = acc[j];
        }
    }
}

// ---------------------------- agg1 in x-space (LDS-table + pk math) --------

__global__ __launch_bounds__(256) void agg1x_kernel(const unsigned short* __restrict__ xb,
                            const float* __restrict__ el, const float* __restrict__ er,
                            const int* __restrict__ srcs, const int* __restrict__ row_start,
                            unsigned short* __restrict__ A1, int N) {
    __shared__ int   s_tbl[4][64];
    __shared__ float a_tbl[4][64][4];
    const int wslot = threadIdx.x >> 6;
    const int lane = threadIdx.x & 63;
    const int n = (blockIdx.x * 256 + threadIdx.x) >> 6;
    if (n >= N) return;
    const int rs = row_start[n];
    const int re = row_start[n + 1];

    // accP[dim][hpair], component j = head 2*hpair+j; dP[hpair] = denominators
    float2v accP[2][2];
    accP[0][0] = (float2v){0.f, 0.f}; accP[0][1] = (float2v){0.f, 0.f};
    accP[1][0] = (float2v){0.f, 0.f}; accP[1][1] = (float2v){0.f, 0.f};
    float2v dP[2];
    dP[0] = (float2v){0.f, 0.f}; dP[1] = (float2v){0.f, 0.f};

    if (re > rs) {
        const float4 ern = *(const float4*)(er + (size_t)n * 4);
        for (int base = rs; base < re; base += 64) {
            const int cnt = (re - base) < 64 ? (re - base) : 64;
            asm volatile("s_waitcnt lgkmcnt(0)" ::: "memory");
            if (lane < cnt) {
                int sv = srcs[base + lane];
                float4 ev = *(const float4*)(el + (size_t)sv * 4);
                float4 av;
                av.x = __expf(lrelu(ev.x + ern.x));
                av.y = __expf(lrelu(ev.y + ern.y));
                av.z = __expf(lrelu(ev.z + ern.z));
                av.w = __expf(lrelu(ev.w + ern.w));
                s_tbl[wslot][lane] = sv;
                *(float4*)&a_tbl[wslot][lane][0] = av;
            }
            asm volatile("s_waitcnt lgkmcnt(0)" ::: "memory");
            int i = 0;
            for (; i + 4 <= cnt; i += 4) {
                int s0 = s_tbl[wslot][i],     s1 = s_tbl[wslot][i + 1];
                int s2 = s_tbl[wslot][i + 2], s3 = s_tbl[wslot][i + 3];
                float4 w0 = *(const float4*)&a_tbl[wslot][i][0];
                float4 w1 = *(const float4*)&a_tbl[wslot][i + 1][0];
                float4 w2 = *(const float4*)&a_tbl[wslot][i + 2][0];
                float4 w3 = *(const float4*)&a_tbl[wslot][i + 3][0];
                unsigned int v0 = *(const unsigned int*)(xb + (size_t)s0 * 128 + lane * 2);
                unsigned int v1 = *(const unsigned int*)(xb + (size_t)s1 * 128 + lane * 2);
                unsigned int v2 = *(const unsigned int*)(xb + (size_t)s2 * 128 + lane * 2);
                unsigned int v3 = *(const unsigned int*)(xb + (size_t)s3 * 128 + lane * 2);
                pk_step(accP[0][0], accP[0][1], accP[1][0], accP[1][1], dP[0], dP[1], w0, v0);
                pk_step(accP[0][0], accP[0][1], accP[1][0], accP[1][1], dP[0], dP[1], w1, v1);
                pk_step(accP[0][0], accP[0][1], accP[1][0], accP[1][1], dP[0], dP[1], w2, v2);
                pk_step(accP[0][0], accP[0][1], accP[1][0], accP[1][1], dP[0], dP[1], w3, v3);
            }
            for (; i < cnt; ++i) {
                int s0 = s_tbl[wslot][i];
                float4 w = *(const float4*)&a_tbl[wslot][i][0];
                unsigned int v = *(const unsigned int*)(xb + (size_t)s0 * 128 + lane * 2);
                pk_step(accP[0][0], accP[0][1], accP[1][0], accP[1][1], dP[0], dP[1], w, v);
            }
        }
        float i0 = 1.f / dP[0][0], i1 = 1.f / dP[0][1];
        float i2 = 1.f / dP[1][0], i3 = 1.f / dP[1][1];
        accP[0][0][0] *= i0; accP[1][0][0] *= i0;
        accP[0][0][1] *= i1; accP[1][0][1] *= i1;
        accP[0][1][0] *= i2; accP[1][1][0] *= i2;
        accP[0][1][1] *= i3; accP[1][1][1] *= i3;
    }
    unsigned int pk;
    pk = (unsigned int)f2bf(accP[0][0][0]) | ((unsigned int)f2bf(accP[1][0][0]) << 16);
    *(unsigned int*)(A1 + (size_t)n * 512 + 0 * 128 + lane * 2) = pk;
    pk = (unsigned int)f2bf(accP[0][0][1]) | ((unsigned int)f2bf(accP[1][0][1]) << 16);
    *(unsigned int*)(A1 + (size_t)n * 512 + 1 * 128 + lane * 2) = pk;
    pk = (unsigned int)f2bf(accP[0][1][0]) | ((unsigned int)f2bf(accP[1][1][0]) << 16);
    *(unsigned int*)(A1 + (size_t)n * 512 + 2 * 128 + lane * 2) = pk;
    pk = (unsigned int)f2bf(accP[0][1][1]) | ((unsigned int)f2bf(accP[1][1][1]) << 16);
    *(unsigned int*)(A1 + (size_t)n * 512 + 3 * 128 + lane * 2) = pk;
}

// ---------------------------- per-head GEMM1 (bf16 MFMA, 128 rows) ---------

__global__ __launch_bounds__(256) void gemm1h_kernel(
        const unsigned short* __restrict__ A1,    // [N][4][128] bf16
        const unsigned short* __restrict__ W1th,  // [4][64][128] bf16
        const float* __restrict__ b1,             // [256] f32
        unsigned short* __restrict__ h1rb,        // [N][256] bf16
        int N) {
    constexpr int KP = 136;
    __shared__ unsigned short As[128 * KP];
    __shared__ unsigned short Bs[64 * KP];
    const int tid = threadIdx.x;
    const int wid = tid >> 6;
    const int lane = tid & 63;
    const int r0 = blockIdx.x * 128;
    const int h = blockIdx.z;

    for (int ch = tid; ch < 128 * 16; ch += 256) {
        int row = ch >> 4, kc = ch & 15;
        int gr = r0 + row;
        short8 v = {};
        if (gr < N) v = *(const short8*)(A1 + (size_t)gr * 512 + h * 128 + kc * 8);
        *(short8*)(As + row * KP + kc * 8) = v;
    }
    for (int ch = tid; ch < 64 * 16; ch += 256) {
        int row = ch >> 4, kc = ch & 15;
        *(short8*)(Bs + row * KP + kc * 8) =
            *(const short8*)(W1th + (size_t)h * 8192 + row * 128 + kc * 8);
    }
    __syncthreads();

    float4v acc[8];
    #pragma unroll
    for (int fr = 0; fr < 8; ++fr) acc[fr] = (float4v){0.f, 0.f, 0.f, 0.f};

    const int lr = lane & 15;
    const int lk = (lane >> 4) * 8;
    const int cw = wid * 16;

    #pragma unroll
    for (int ks = 0; ks < 128; ks += 32) {
        short8 bfr = *(const short8*)(Bs + (cw + lr) * KP + ks + lk);
        #pragma unroll
        for (int fr = 0; fr < 8; ++fr) {
            short8 af = *(const short8*)(As + (fr * 16 + lr) * KP + ks + lk);
            acc[fr] = __builtin_amdgcn_mfma_f32_16x16x32_bf16(af, bfr, acc[fr], 0, 0, 0);
        }
    }

    const int col = h * 64 + cw + lr;
    const float bias = b1[col];
    const int rbase = r0 + (lane >> 4) * 4;
    #pragma unroll
    for (int fr = 0; fr < 8; ++fr) {
        #pragma unroll
        for (int j = 0; j < 4; ++j) {
            int row = rbase + fr * 16 + j;
            if (row < N)
                h1rb[(size_t)row * 256 + col] = f2bf(fmaxf(acc[fr][j] + bias, 0.f));
        }
    }
}

// ---------------------------- GEMM2 (bf16 MFMA) ----------------------------

template <int K, int MSLICE>
__global__ __launch_bounds__(256) void mfma_gemm_kernel(
        const unsigned short* __restrict__ A,   // [N][K] bf16
        const unsigned short* __restrict__ Bt,  // [Mtot][K] bf16
        unsigned short* __restrict__ C,         // [N][Mtot] bf16
        int N, int Mtot) {
    constexpr int KP = K + 8;
    constexpr int CF = MSLICE / 64;
    constexpr int KC = K / 8;
    __shared__ unsigned short As[64 * KP];
    __shared__ unsigned short Bs[MSLICE * KP];
    const int tid = threadIdx.x;
    const int wid = tid >> 6;
    const int lane = tid & 63;
    const int r0 = blockIdx.x * 64;
    const int c0 = blockIdx.y * MSLICE;

    for (int ch = tid; ch < 64 * KC; ch += 256) {
        int row = ch / KC, kc = ch - row * KC;
        int gr = r0 + row;
        short8 v = {};
        if (gr < N) v = *(const short8*)(A + (size_t)gr * K + kc * 8);
        *(short8*)(As + row * KP + kc * 8) = v;
    }
    for (int ch = tid; ch < MSLICE * KC; ch += 256) {
        int row = ch / KC, kc = ch - row * KC;
        *(short8*)(Bs + row * KP + kc * 8) =
            *(const short8*)(Bt + (size_t)(c0 + row) * K + kc * 8);
    }
    __syncthreads();

    float4v acc[4][CF];
    #pragma unroll
    for (int fr = 0; fr < 4; ++fr)
        #pragma unroll
        for (int cf = 0; cf < CF; ++cf)
            acc[fr][cf] = (float4v){0.f, 0.f, 0.f, 0.f};

    const int lr = lane & 15;
    const int lk = (lane >> 4) * 8;
    const int cw = wid * (MSLICE / 4);

    #pragma unroll
    for (int ks = 0; ks < K; ks += 32) {
        short8 af[4], bfr[CF];
        #pragma unroll
        for (int fr = 0; fr < 4; ++fr)
            af[fr] = *(const short8*)(As + (fr * 16 + lr) * KP + ks + lk);
        #pragma unroll
        for (int cf = 0; cf < CF; ++cf)
            bfr[cf] = *(const short8*)(Bs + (cw + cf * 16 + lr) * KP + ks + lk);
        #pragma unroll
        for (int fr = 0; fr < 4; ++fr)
            #pragma unroll
            for (int cf = 0; cf < CF; ++cf)
                acc[fr][cf] = __builtin_amdgcn_mfma_f32_16x16x32_bf16(
                    af[fr], bfr[cf], acc[fr][cf], 0, 0, 0);
    }

    const int rbase = r0 + (lane >> 4) * 4;
    #pragma unroll
    for (int fr = 0; fr < 4; ++fr) {
        #pragma unroll
        for (int cf = 0; cf < CF; ++cf) {
            int col = c0 + cw + cf * 16 + lr;
            #pragma unroll
            for (int j = 0; j < 4; ++j) {
                int row = rbase + fr * 16 + j;
                if (row < N)
                    C[(size_t)row * Mtot + col] = f2bf(acc[fr][cf][j]);
            }
        }
    }
}

// ---------------------------- agg2 (H=1, D=128, LDS-table) -----------------

__global__ __launch_bounds__(256) void agg2_kernel(const unsigned short* __restrict__ hb,
                           const float* __restrict__ el, const float* __restrict__ er,
                           const int* __restrict__ srcs, const int* __restrict__ row_start,
                           const float* __restrict__ bias, float* __restrict__ out, int N) {
    __shared__ uint2 t_tbl[4][64];
    const int wslot = threadIdx.x >> 6;
    const int lane = threadIdx.x & 63;
    const int n = (blockIdx.x * 256 + threadIdx.x) >> 6;
    if (n >= N) return;
    const int rs = row_start[n];
    const int re = row_start[n + 1];

    float acc0 = 0.f, acc1 = 0.f, d = 0.f;

    if (re > rs) {
        const float ern = er[n];
        for (int base = rs; base < re; base += 64) {
            const int cnt = (re - base) < 64 ? (re - base) : 64;
            asm volatile("s_waitcnt lgkmcnt(0)" ::: "memory");
            if (lane < cnt) {
                int sv = srcs[base + lane];
                float a = __expf(lrelu(el[sv] + ern));
                t_tbl[wslot][lane] = make_uint2((unsigned int)sv, __float_as_uint(a));
            }
            asm volatile("s_waitcnt lgkmcnt(0)" ::: "memory");
            int i = 0;
            for (; i + 4 <= cnt; i += 4) {
                uint2 t0 = t_tbl[wslot][i],     t1 = t_tbl[wslot][i + 1];
                uint2 t2 = t_tbl[wslot][i + 2], t3 = t_tbl[wslot][i + 3];
                float w0 = __uint_as_float(t0.y), w1 = __uint_as_float(t1.y);
                float w2 = __uint_as_float(t2.y), w3 = __uint_as_float(t3.y);
                unsigned int v0 = *(const unsigned int*)(hb + (size_t)t0.x * 128 + lane * 2);
                unsigned int v1 = *(const unsigned int*)(hb + (size_t)t1.x * 128 + lane * 2);
                unsigned int v2 = *(const unsigned int*)(hb + (size_t)t2.x * 128 + lane * 2);
                unsigned int v3 = *(const unsigned int*)(hb + (size_t)t3.x * 128 + lane * 2);
                d += w0 + w1 + w2 + w3;
                acc0 += w0 * bf2f(v0 & 0xffffu) + w1 * bf2f(v1 & 0xffffu) +
                        w2 * bf2f(v2 & 0xffffu) + w3 * bf2f(v3 & 0xffffu);
                acc1 += w0 * bf2f(v0 >> 16) + w1 * bf2f(v1 >> 16) +
                        w2 * bf2f(v2 >> 16) + w3 * bf2f(v3 >> 16);
            }
            for (; i < cnt; ++i) {
                uint2 t = t_tbl[wslot][i];
                float w = __uint_as_float(t.y);
                unsigned int v = *(const unsigned int*)(hb + (size_t)t.x * 128 + lane * 2);
                d += w;
                acc0 += w * bf2f(v & 0xffffu);
                acc1 += w * bf2f(v >> 16);
            }
        }
        float invd = 1.f / d;
        acc0 *= invd; acc1 *= invd;
    }
    float o0 = acc0 + bias[lane * 2];
    float o1 = acc1 + bias[lane * 2 + 1];
    *(float2*)(out + (size_t)n * 128 + lane * 2) = make_float2(o0, o1);
}

// ---------------------------------------------------------------------------

extern "C" void kernel_launch(void* const* d_in, const int* in_sizes, int n_in,
                              void* d_out, int out_size, void* d_ws, size_t ws_size,
                              hipStream_t stream) {
    const float* x   = (const float*)d_in[0];
    const int*   src = (const int*)d_in[1];
    const int*   dst = (const int*)d_in[2];
    const float* W1  = (const float*)d_in[3];
    const float* al1 = (const float*)d_in[4];
    const float* ar1 = (const float*)d_in[5];
    const float* b1  = (const float*)d_in[6];
    const float* W2  = (const float*)d_in[7];
    const float* al2 = (const float*)d_in[8];
    const float* ar2 = (const float*)d_in[9];
    const float* b2  = (const float*)d_in[10];
    float* out = (float*)d_out;

    const int N = in_sizes[0] / 128;  // 50000
    const int E = in_sizes[1];        // 800000

    char* ws = (char*)d_ws;
    size_t oXB   = 0;                              // xb bf16 [N*128]
    size_t oA1   = oXB + (size_t)N * 128 * 2;      // A1 bf16 [N*4*128] (h2b aliases)
    size_t oH1R  = oA1 + (size_t)N * 512 * 2;      // h1rb bf16 [N*256]
    size_t oW1th = oH1R + (size_t)N * 256 * 2;     // [4*64*128] bf16
    size_t oQt1  = oW1th + 32768 * 2;              // [16*128] bf16
    size_t oQt2  = oQt1 + 2048 * 2;                // [16*128] bf16
    size_t oW2t  = oQt2 + 2048 * 2;                // [128*256] bf16
    size_t oEl1  = oW2t + 32768 * 2;               // [N*4] f32
    size_t oEr1  = oEl1 + (size_t)N * 4 * 4;
    size_t oEl2  = oEr1 + (size_t)N * 4 * 4;       // [N] f32
    size_t oEr2  = oEl2 + (size_t)N * 4;
    size_t oCnt  = oEr2 + (size_t)N * 4;           // cnt [N], fill [N] adjacent
    size_t oFill = oCnt + (size_t)N * 4;
    size_t oRow  = oFill + (size_t)N * 4;
    size_t oBsum = oRow + (((size_t)(N + 1) * 4 + 15) & ~(size_t)15);
    size_t oSrcs = oBsum + 256 * 4;                // [E]

    unsigned short* xb   = (unsigned short*)(ws + oXB);
    unsigned short* A1   = (unsigned short*)(ws + oA1);
    unsigned short* h2b  = (unsigned short*)(ws + oA1);  // reuse: A1 dead after gemm1h
    unsigned short* h1rb = (unsigned short*)(ws + oH1R);
    unsigned short* w1th = (unsigned short*)(ws + oW1th);
    unsigned short* qt1  = (unsigned short*)(ws + oQt1);
    unsigned short* qt2  = (unsigned short*)(ws + oQt2);
    unsigned short* w2t  = (unsigned short*)(ws + oW2t);
    float* el1 = (float*)(ws + oEl1);
    float* er1 = (float*)(ws + oEr1);
    float* el2 = (float*)(ws + oEl2);
    float* er2 = (float*)(ws + oEr2);
    int* cnt       = (int*)(ws + oCnt);
    int* fill      = (int*)(ws + oFill);
    int* row_start = (int*)(ws + oRow);
    int* bsum      = (int*)(ws + oBsum);
    int* srcs      = (int*)(ws + oSrcs);

    const int nch = (N + 255) / 256;          // 196
    const int nhistblk = (E + 255) / 256;     // 3125

    // ---- CSR build + weight prep ----
    hipMemsetAsync(cnt, 0, (size_t)N * 8, stream);  // cnt + fill (adjacent)
    histwprep_kernel<<<nhistblk + 272, 256, 0, stream>>>(
        dst, cnt, E, nhistblk, W1, al1, ar1, W2, al2, ar2, w1th, qt1, qt2, w2t);
    scan_a_kernel<<<nch, 256, 0, stream>>>(cnt, bsum, N);
    scan_c_kernel<<<nch, 256, 0, stream>>>(cnt, bsum, row_start, N, E, nch);
    scatter_kernel<<<nhistblk, 256, 0, stream>>>(src, dst, row_start, fill, srcs, E);

    const int nrowb = (N + 63) / 64;     // 782
    const int nrowb2 = (N + 127) / 128;  // 391
    const int nwaveb = (N + 3) / 4;

    // ---- layer 1 ----
    xdots_kernel<<<nrowb, 256, 0, stream>>>(x, qt1, xb, el1, er1, N);
    agg1x_kernel<<<nwaveb, 256, 0, stream>>>(xb, el1, er1, srcs, row_start, A1, N);
    gemm1h_kernel<<<dim3(nrowb2, 1, 4), 256, 0, stream>>>(A1, w1th, b1, h1rb, N);

    // ---- layer 2 ----
    mfma_gemm_kernel<256, 64><<<dim3(nrowb, 2), 256, 0, stream>>>(h1rb, w2t, h2b, N, 128);
    dots2_kernel<<<nrowb, 256, 0, stream>>>(h2b, qt2, el2, er2, N);
    agg2_kernel<<<nwaveb, 256, 0, stream>>>(h2b, el2, er2, srcs, row_start, b2, out, N);
}